// Round 5
// baseline (121.970 us; speedup 1.0000x reference)
//
#include <hip/hip_runtime.h>
#include <hip/hip_bf16.h>

#define B_    2
#define CIN   4
#define COUT  8
#define KK    4
#define DD    2
#define NN    224
#define FDIM  128
#define NH    218
#define NSUB  (NH*NH)         // 47524
#define NPERM 24
#define NROWS (B_*COUT*CIN)   // 64 softmax rows
#define NSUB4 (NSUB/4)        // 11881 float4s per row
#define CH4   512             // float4s per chunk (final pass)
#define MB    ((NSUB4 + CH4 - 1) / CH4)   // 24 chunk-blocks per row
#define OG    2               // o-split; each thread handles COUT/OG = 4 o's
#define NCHUNK ((NSUB + 255) / 256)       // 186 s-chunks (fused stats granularity)
#define NEGBIG (-3.4e38f)

__device__ static constexpr int PERM[NPERM][4] = {
  {0,1,2,3},{0,1,3,2},{0,2,1,3},{0,2,3,1},{0,3,1,2},{0,3,2,1},
  {1,0,2,3},{1,0,3,2},{1,2,0,3},{1,2,3,0},{1,3,0,2},{1,3,2,0},
  {2,0,1,3},{2,0,3,1},{2,1,0,3},{2,1,3,0},{2,3,0,1},{2,3,1,0},
  {3,0,1,2},{3,0,2,1},{3,1,0,2},{3,1,2,0},{3,2,0,1},{3,2,1,0}
};

// one wave per (b,f): lanes split r, shuffle-reduce
__global__ __launch_bounds__(64) void hmean_kernel(const float* __restrict__ features,
                                                   float* __restrict__ out) {
  int bf = blockIdx.x;
  int b = bf / FDIM, f = bf - b * FDIM;
  int lane = threadIdx.x;
  const float* fb = features + (size_t)b * NN * FDIM + f;
  float acc = 0.f;
  for (int r = lane; r < NN; r += 64) {
    int w = 0;
#pragma unroll
    for (int a = 0; a < KK; ++a) {
      int i0 = r - a * DD;
      if (0 <= i0 && i0 < NH) w++;
    }
    acc += (float)w * fb[(size_t)r * FDIM];
  }
#pragma unroll
  for (int off = 32; off > 0; off >>= 1) acc += __shfl_down(acc, off, 64);
  if (lane == 0) out[bf] = acc * (2.0f / (float)NH);
}

// grid: (NCHUNK, B*CIN*OG). Each thread: one s, one (b,ci), COUT/OG o's.
// Fused: per-block (m, sumexp) stats per row written to partial[row*NCHUNK+chunk].
__global__ __launch_bounds__(256) void sims_kernel(
    const float* __restrict__ graph, const float* __restrict__ types,
    const float* __restrict__ ksA, const float* __restrict__ krA,
    const float* __restrict__ kcA, float* __restrict__ simsOut,
    float* __restrict__ partial)
{
  __shared__ float ls[COUT * CIN * 16];
  __shared__ float lr[COUT * CIN * 4];
  __shared__ float lc[COUT * CIN * 4];
  __shared__ float lK2[COUT * CIN];
  __shared__ float red[4 * 4];      // [wave][slot] scratch for cross-wave combine
  int t = threadIdx.x;
  for (int i = t; i < COUT * CIN * 16; i += 256) ls[i] = ksA[i];
  for (int i = t; i < COUT * CIN * 4; i += 256) { lr[i] = krA[i]; lc[i] = kcA[i]; }
  __syncthreads();
  if (t < COUT * CIN) {
    float k2 = 0.f;
#pragma unroll
    for (int u = 0; u < 16; ++u) k2 += ls[t * 16 + u] * ls[t * 16 + u];
#pragma unroll
    for (int u = 0; u < 4; ++u) k2 += lr[t * 4 + u] * lr[t * 4 + u] + lc[t * 4 + u] * lc[t * 4 + u];
    lK2[t] = k2;
  }
  __syncthreads();

  int s_raw = blockIdx.x * 256 + t;
  bool valid = (s_raw < NSUB);
  int s = valid ? s_raw : (NSUB - 1);   // clamp for address safety
  int yi  = blockIdx.y;                 // 0..B_*CIN*OG-1
  int og  = yi >> 3;
  int bci = yi & 7;
  int b   = bci >> 2;
  int ci  = bci & 3;
  int ii  = s / NH;
  int jj  = s - ii * NH;

  const float* gi = graph + ((size_t)b * CIN + ci) * NN * NN;
  const float* ti = types + ((size_t)b * CIN + ci) * NN;

  float subv[16], rtv[4], ctv[4];
  float G2 = 0.f, T2r = 0.f, T2c = 0.f;
#pragma unroll
  for (int a = 0; a < KK; ++a) {
    const float* row = gi + (size_t)(ii + a * DD) * NN + jj;
#pragma unroll
    for (int bb = 0; bb < KK; ++bb) {
      float v = row[bb * DD];
      subv[a * 4 + bb] = v;
      G2 += v * v;
    }
    float rv = ti[ii + a * DD];
    float cv = ti[jj + a * DD];
    rtv[a] = rv; ctv[a] = cv;
    T2r += rv * rv; T2c += cv * cv;
  }
  float base0 = G2 + T2r + T2c;

  int wave = t >> 6, lane = t & 63;

#pragma unroll 1
  for (int oo = 0; oo < COUT / OG; ++oo) {
    int o = og * (COUT / OG) + oo;
    int oc = o * CIN + ci;
    const float* pS = ls + oc * 16;
    const float* pR = lr + oc * 4;
    const float* pC = lc + oc * 4;
    float kS[16], kR[4], kC[4];
#pragma unroll
    for (int u = 0; u < 16; ++u) kS[u] = pS[u];
#pragma unroll
    for (int u = 0; u < 4; ++u) { kR[u] = pR[u]; kC[u] = pC[u]; }

    // C1[a][a'] = diag + row + col contribution for mapping a->a'
    float C1[16];
#pragma unroll
    for (int a = 0; a < 4; ++a)
#pragma unroll
      for (int ap = 0; ap < 4; ++ap)
        C1[a * 4 + ap] = subv[a * 4 + a] * kS[ap * 4 + ap]
                       + rtv[a] * kR[ap] + ctv[a] * kC[ap];

    float maxcr = NEGBIG;
#pragma unroll
    for (int p = 0; p < NPERM; ++p) {
      const int p0 = PERM[p][0], p1 = PERM[p][1], p2 = PERM[p][2], p3 = PERM[p][3];
      float cr = C1[0 * 4 + p0] + C1[1 * 4 + p1] + C1[2 * 4 + p2] + C1[3 * 4 + p3];
      cr += subv[0*4+1] * kS[p0*4+p1];
      cr += subv[0*4+2] * kS[p0*4+p2];
      cr += subv[0*4+3] * kS[p0*4+p3];
      cr += subv[1*4+0] * kS[p1*4+p0];
      cr += subv[1*4+2] * kS[p1*4+p2];
      cr += subv[1*4+3] * kS[p1*4+p3];
      cr += subv[2*4+0] * kS[p2*4+p0];
      cr += subv[2*4+1] * kS[p2*4+p1];
      cr += subv[2*4+3] * kS[p2*4+p3];
      cr += subv[3*4+0] * kS[p3*4+p0];
      cr += subv[3*4+1] * kS[p3*4+p1];
      cr += subv[3*4+2] * kS[p3*4+p2];
      maxcr = fmaxf(maxcr, cr);
    }
    float best = base0 + lK2[oc] - 2.0f * maxcr;
    if (valid)
      simsOut[(((size_t)b * COUT + o) * CIN + ci) * NSUB + s] = best;

    // ---- fused per-block softmax stats for this row ----
    float bm = valid ? best : NEGBIG;
    float m = bm;
#pragma unroll
    for (int off = 32; off > 0; off >>= 1) m = fmaxf(m, __shfl_down(m, off, 64));
    if (lane == 0) red[wave] = m;
    __syncthreads();
    float m_blk = fmaxf(fmaxf(red[0], red[1]), fmaxf(red[2], red[3]));
    float e = valid ? __expf(bm - m_blk) : 0.f;
#pragma unroll
    for (int off = 32; off > 0; off >>= 1) e += __shfl_down(e, off, 64);
    __syncthreads();           // red reuse safety
    if (lane == 0) red[4 + wave] = e;
    __syncthreads();
    if (t == 0) {
      float l_blk = red[4] + red[5] + red[6] + red[7];
      int rowc = (((b * COUT + o) * CIN + ci) * NCHUNK + blockIdx.x) * 2;
      partial[rowc]     = m_blk;
      partial[rowc + 1] = l_blk;
    }
    __syncthreads();
  }
}

// combine NCHUNK partials per row -> (M, 1/S). grid = NROWS, 256 threads.
__global__ __launch_bounds__(256) void softmax_combine(const float* __restrict__ partial,
                                                       float* __restrict__ stats) {
  int row = blockIdx.x;
  int t = threadIdx.x;
  float m = NEGBIG, l = 0.f;
  if (t < NCHUNK) {
    m = partial[(row * NCHUNK + t) * 2];
    l = partial[(row * NCHUNK + t) * 2 + 1];
  }
  __shared__ float ms[256], lsum[256];
  ms[t] = m; lsum[t] = l;
  __syncthreads();
  for (int off = 128; off > 0; off >>= 1) {
    if (t < off) {
      float m2 = ms[t + off], l2 = lsum[t + off];
      float M = fmaxf(ms[t], m2);
      lsum[t] = lsum[t] * __expf(ms[t] - M) + l2 * __expf(m2 - M);
      ms[t] = M;
    }
    __syncthreads();
  }
  if (t == 0) { stats[2 * row] = ms[0]; stats[2 * row + 1] = 1.0f / lsum[0]; }
}

// final: rewrite in place, float4
__global__ __launch_bounds__(256) void softmax_final(float* __restrict__ sims,
                                                     const float* __restrict__ stats) {
  int blk = blockIdx.x;
  int row = blk / MB;
  int ch  = blk - row * MB;
  int base4 = ch * CH4;
  int n4 = NSUB4 - base4; if (n4 > CH4) n4 = CH4;
  float4* rp = (float4*)(sims + (size_t)row * NSUB) + base4;
  float M = stats[2 * row], invS = stats[2 * row + 1];
  const float scale = 1.0f / (float)NSUB;
  for (int i = threadIdx.x; i < n4; i += 256) {
    float4 v = rp[i];
    v.x = (1.0f - __expf(v.x - M) * invS) * scale;
    v.y = (1.0f - __expf(v.y - M) * invS) * scale;
    v.z = (1.0f - __expf(v.z - M) * invS) * scale;
    v.w = (1.0f - __expf(v.w - M) * invS) * scale;
    rp[i] = v;
  }
}

extern "C" void kernel_launch(void* const* d_in, const int* in_sizes, int n_in,
                              void* d_out, int out_size, void* d_ws, size_t ws_size,
                              hipStream_t stream) {
  const float* graph    = (const float*)d_in[0];
  const float* types    = (const float*)d_in[1];
  const float* features = (const float*)d_in[2];
  const float* ks       = (const float*)d_in[3];
  const float* kr       = (const float*)d_in[4];
  const float* kc       = (const float*)d_in[5];
  float* out  = (float*)d_out;
  float* sims = out + B_ * FDIM;

  float* partial = (float*)d_ws;                    // NROWS*NCHUNK*2 floats
  float* stats   = partial + NROWS * NCHUNK * 2;    // NROWS*2 floats

  hmean_kernel<<<B_ * FDIM, 64, 0, stream>>>(features, out);
  dim3 sgrid(NCHUNK, B_ * CIN * OG);
  sims_kernel<<<sgrid, 256, 0, stream>>>(graph, types, ks, kr, kc, sims, partial);
  softmax_combine<<<NROWS, 256, 0, stream>>>(partial, stats);
  softmax_final<<<NROWS * MB, 256, 0, stream>>>(sims, stats);
}

// Round 6
// 108.189 us; speedup vs baseline: 1.1274x; 1.1274x over previous
//
#include <hip/hip_runtime.h>
#include <hip/hip_bf16.h>

#define B_    2
#define CIN   4
#define COUT  8
#define KK    4
#define DD    2
#define NN    224
#define FDIM  128
#define NH    218
#define NSUB  (NH*NH)         // 47524
#define NPERM 24
#define NROWS (B_*COUT*CIN)   // 64 softmax rows
#define NSUB4 (NSUB/4)        // 11881 float4s per row
#define CH4   512             // float4s per chunk (final pass)
#define MB    ((NSUB4 + CH4 - 1) / CH4)   // 24 chunk-blocks per row
#define OG    2               // o-split; each thread handles COUT/OG = 4 o's
#define NCH2  ((NSUB + 511) / 512)        // 93 s-chunks (512 s per block, 2/thread)
#define NW    4               // waves per block
#define NEGBIG (-3.4e38f)

typedef float v2f __attribute__((ext_vector_type(2)));

__device__ static constexpr int PERM[NPERM][4] = {
  {0,1,2,3},{0,1,3,2},{0,2,1,3},{0,2,3,1},{0,3,1,2},{0,3,2,1},
  {1,0,2,3},{1,0,3,2},{1,2,0,3},{1,2,3,0},{1,3,0,2},{1,3,2,0},
  {2,0,1,3},{2,0,3,1},{2,1,0,3},{2,1,3,0},{2,3,0,1},{2,3,1,0},
  {3,0,1,2},{3,0,2,1},{3,1,0,2},{3,1,2,0},{3,2,0,1},{3,2,1,0}
};

// one wave per (b,f): lanes split r, shuffle-reduce
__global__ __launch_bounds__(64) void hmean_kernel(const float* __restrict__ features,
                                                   float* __restrict__ out) {
  int bf = blockIdx.x;
  int b = bf / FDIM, f = bf - b * FDIM;
  int lane = threadIdx.x;
  const float* fb = features + (size_t)b * NN * FDIM + f;
  float acc = 0.f;
  for (int r = lane; r < NN; r += 64) {
    int w = 0;
#pragma unroll
    for (int a = 0; a < KK; ++a) {
      int i0 = r - a * DD;
      if (0 <= i0 && i0 < NH) w++;
    }
    acc += (float)w * fb[(size_t)r * FDIM];
  }
#pragma unroll
  for (int off = 32; off > 0; off >>= 1) acc += __shfl_down(acc, off, 64);
  if (lane == 0) out[bf] = acc * (2.0f / (float)NH);
}

// grid: (NCH2, B*CIN*OG). Each thread: s0 = blk*512+t and s1 = s0+256 (packed
// as float2 -> v_pk_fma_f32), COUT/OG o's. Per-wave softmax partials (m,l).
__global__ __launch_bounds__(256) void sims_kernel(
    const float* __restrict__ graph, const float* __restrict__ types,
    const float* __restrict__ ksA, const float* __restrict__ krA,
    const float* __restrict__ kcA, float* __restrict__ simsOut,
    float* __restrict__ partial)
{
  __shared__ float ls[COUT * CIN * 16];
  __shared__ float lr[COUT * CIN * 4];
  __shared__ float lc[COUT * CIN * 4];
  __shared__ float lK2[COUT * CIN];
  int t = threadIdx.x;
  for (int i = t; i < COUT * CIN * 16; i += 256) ls[i] = ksA[i];
  for (int i = t; i < COUT * CIN * 4; i += 256) { lr[i] = krA[i]; lc[i] = kcA[i]; }
  __syncthreads();
  if (t < COUT * CIN) {
    float k2 = 0.f;
#pragma unroll
    for (int u = 0; u < 16; ++u) k2 += ls[t * 16 + u] * ls[t * 16 + u];
#pragma unroll
    for (int u = 0; u < 4; ++u) k2 += lr[t * 4 + u] * lr[t * 4 + u] + lc[t * 4 + u] * lc[t * 4 + u];
    lK2[t] = k2;
  }
  __syncthreads();

  int s0r = blockIdx.x * 512 + t;
  int s1r = s0r + 256;
  bool v0 = (s0r < NSUB), v1 = (s1r < NSUB);
  int s0 = v0 ? s0r : (NSUB - 1);
  int s1 = v1 ? s1r : (NSUB - 1);
  int yi  = blockIdx.y;
  int og  = yi >> 3;
  int bci = yi & 7;
  int b   = bci >> 2;
  int ci  = bci & 3;
  int ii0 = s0 / NH, jj0 = s0 - ii0 * NH;
  int ii1 = s1 / NH, jj1 = s1 - ii1 * NH;

  const float* gi = graph + ((size_t)b * CIN + ci) * NN * NN;
  const float* ti = types + ((size_t)b * CIN + ci) * NN;

  v2f subv[16], rtv[4], ctv[4];
  v2f G2 = 0.f, T2r = 0.f, T2c = 0.f;
#pragma unroll
  for (int a = 0; a < KK; ++a) {
    const float* r0 = gi + (size_t)(ii0 + a * DD) * NN + jj0;
    const float* r1 = gi + (size_t)(ii1 + a * DD) * NN + jj1;
#pragma unroll
    for (int bb = 0; bb < KK; ++bb) {
      v2f v; v.x = r0[bb * DD]; v.y = r1[bb * DD];
      subv[a * 4 + bb] = v;
      G2 += v * v;
    }
    v2f rv; rv.x = ti[ii0 + a * DD]; rv.y = ti[ii1 + a * DD];
    v2f cv; cv.x = ti[jj0 + a * DD]; cv.y = ti[jj1 + a * DD];
    rtv[a] = rv; ctv[a] = cv;
    T2r += rv * rv; T2c += cv * cv;
  }
  v2f base0 = G2 + T2r + T2c;

  int wave = t >> 6, lane = t & 63;

#pragma unroll 1
  for (int oo = 0; oo < COUT / OG; ++oo) {
    int o = og * (COUT / OG) + oo;
    int oc = o * CIN + ci;
    float kS[16], kR[4], kC[4];
    {
      const float4* pS4 = (const float4*)(ls + oc * 16);
#pragma unroll
      for (int u = 0; u < 4; ++u) {
        float4 q = pS4[u];
        kS[u*4+0] = q.x; kS[u*4+1] = q.y; kS[u*4+2] = q.z; kS[u*4+3] = q.w;
      }
      float4 qr = *(const float4*)(lr + oc * 4);
      kR[0] = qr.x; kR[1] = qr.y; kR[2] = qr.z; kR[3] = qr.w;
      float4 qc = *(const float4*)(lc + oc * 4);
      kC[0] = qc.x; kC[1] = qc.y; kC[2] = qc.z; kC[3] = qc.w;
    }

    // C1[a][a'] = diag + row + col contribution for mapping a->a'  (packed 2s)
    v2f C1[16];
#pragma unroll
    for (int a = 0; a < 4; ++a)
#pragma unroll
      for (int ap = 0; ap < 4; ++ap)
        C1[a * 4 + ap] = subv[a * 4 + a] * kS[ap * 4 + ap]
                       + rtv[a] * kR[ap] + ctv[a] * kC[ap];

    v2f maxcr = NEGBIG;
#pragma unroll
    for (int p = 0; p < NPERM; ++p) {
      const int p0 = PERM[p][0], p1 = PERM[p][1], p2 = PERM[p][2], p3 = PERM[p][3];
      v2f cr = C1[0 * 4 + p0] + C1[1 * 4 + p1] + C1[2 * 4 + p2] + C1[3 * 4 + p3];
      cr += subv[0*4+1] * kS[p0*4+p1];
      cr += subv[0*4+2] * kS[p0*4+p2];
      cr += subv[0*4+3] * kS[p0*4+p3];
      cr += subv[1*4+0] * kS[p1*4+p0];
      cr += subv[1*4+2] * kS[p1*4+p2];
      cr += subv[1*4+3] * kS[p1*4+p3];
      cr += subv[2*4+0] * kS[p2*4+p0];
      cr += subv[2*4+1] * kS[p2*4+p1];
      cr += subv[2*4+3] * kS[p2*4+p3];
      cr += subv[3*4+0] * kS[p3*4+p0];
      cr += subv[3*4+1] * kS[p3*4+p1];
      cr += subv[3*4+2] * kS[p3*4+p2];
      maxcr = __builtin_elementwise_max(maxcr, cr);
    }
    v2f best = base0 + lK2[oc] - 2.0f * maxcr;

    int rowIdx = (b * COUT + o) * CIN + ci;
    size_t rowbase = (size_t)rowIdx * NSUB;
    if (v0) simsOut[rowbase + s0r] = best.x;
    if (v1) simsOut[rowbase + s1r] = best.y;

    // per-wave softmax partial (m, l): shuffles only, no syncthreads
    float bm0 = v0 ? best.x : NEGBIG;
    float bm1 = v1 ? best.y : NEGBIG;
    float m = fmaxf(bm0, bm1);
#pragma unroll
    for (int off = 32; off > 0; off >>= 1) m = fmaxf(m, __shfl_down(m, off, 64));
    m = __shfl(m, 0, 64);
    float e = 0.f;
    if (v0) e += __expf(bm0 - m);
    if (v1) e += __expf(bm1 - m);
#pragma unroll
    for (int off = 32; off > 0; off >>= 1) e += __shfl_down(e, off, 64);
    if (lane == 0) {
      int idx = ((rowIdx * NCH2 + blockIdx.x) * NW + wave) * 2;
      partial[idx] = m; partial[idx + 1] = e;
    }
  }
}

// combine NCH2*NW partials per row -> (M, 1/S). grid = NROWS, 256 threads.
__global__ __launch_bounds__(256) void softmax_combine(const float* __restrict__ partial,
                                                       float* __restrict__ stats) {
  int row = blockIdx.x;
  int t = threadIdx.x;
  const float* pp = partial + (size_t)row * NCH2 * NW * 2;
  float m = NEGBIG, l = 0.f;
  for (int i = t; i < NCH2 * NW; i += 256) {
    float mi = pp[2 * i], li = pp[2 * i + 1];
    float M = fmaxf(m, mi);
    l = l * __expf(m - M) + li * __expf(mi - M);
    m = M;
  }
  __shared__ float ms[256], lsv[256];
  ms[t] = m; lsv[t] = l;
  __syncthreads();
  for (int off = 128; off > 0; off >>= 1) {
    if (t < off) {
      float m2 = ms[t + off], l2 = lsv[t + off];
      float M = fmaxf(ms[t], m2);
      lsv[t] = lsv[t] * __expf(ms[t] - M) + l2 * __expf(m2 - M);
      ms[t] = M;
    }
    __syncthreads();
  }
  if (t == 0) { stats[2 * row] = ms[0]; stats[2 * row + 1] = 1.0f / lsv[0]; }
}

// final: rewrite in place, float4
__global__ __launch_bounds__(256) void softmax_final(float* __restrict__ sims,
                                                     const float* __restrict__ stats) {
  int blk = blockIdx.x;
  int row = blk / MB;
  int ch  = blk - row * MB;
  int base4 = ch * CH4;
  int n4 = NSUB4 - base4; if (n4 > CH4) n4 = CH4;
  float4* rp = (float4*)(sims + (size_t)row * NSUB) + base4;
  float M = stats[2 * row], invS = stats[2 * row + 1];
  const float scale = 1.0f / (float)NSUB;
  for (int i = threadIdx.x; i < n4; i += 256) {
    float4 v = rp[i];
    v.x = (1.0f - __expf(v.x - M) * invS) * scale;
    v.y = (1.0f - __expf(v.y - M) * invS) * scale;
    v.z = (1.0f - __expf(v.z - M) * invS) * scale;
    v.w = (1.0f - __expf(v.w - M) * invS) * scale;
    rp[i] = v;
  }
}

extern "C" void kernel_launch(void* const* d_in, const int* in_sizes, int n_in,
                              void* d_out, int out_size, void* d_ws, size_t ws_size,
                              hipStream_t stream) {
  const float* graph    = (const float*)d_in[0];
  const float* types    = (const float*)d_in[1];
  const float* features = (const float*)d_in[2];
  const float* ks       = (const float*)d_in[3];
  const float* kr       = (const float*)d_in[4];
  const float* kc       = (const float*)d_in[5];
  float* out  = (float*)d_out;
  float* sims = out + B_ * FDIM;

  float* partial = (float*)d_ws;                       // NROWS*NCH2*NW*2 floats
  float* stats   = partial + NROWS * NCH2 * NW * 2;    // NROWS*2 floats

  hmean_kernel<<<B_ * FDIM, 64, 0, stream>>>(features, out);
  dim3 sgrid(NCH2, B_ * CIN * OG);
  sims_kernel<<<sgrid, 256, 0, stream>>>(graph, types, ks, kr, kc, sims, partial);
  softmax_combine<<<NROWS, 256, 0, stream>>>(partial, stats);
  softmax_final<<<NROWS * MB, 256, 0, stream>>>(sims, stats);
}

// Round 7
// 103.654 us; speedup vs baseline: 1.1767x; 1.0438x over previous
//
#include <hip/hip_runtime.h>
#include <hip/hip_bf16.h>

#define B_    2
#define CIN   4
#define COUT  8
#define KK    4
#define DD    2
#define NN    224
#define FDIM  128
#define NH    218
#define NSUB  (NH*NH)         // 47524
#define NPERM 24
#define NROWS (B_*COUT*CIN)   // 64 softmax rows
#define NSUB4 (NSUB/4)        // 11881 float4s per row
#define CH4   512             // float4s per chunk (final pass)
#define MB    ((NSUB4 + CH4 - 1) / CH4)   // 24 chunk-blocks per row
#define OG    2               // o-split; each thread handles COUT/OG = 4 o's
#define NCH2  ((NSUB + 511) / 512)        // 93 s-chunks (512 s per block, 2/thread)
#define NW    4               // waves per block
#define NPART (NCH2*NW)       // 372 partials per row
#define NEGBIG (-3.4e38f)

typedef float v2f __attribute__((ext_vector_type(2)));

__device__ static constexpr int PERM[NPERM][4] = {
  {0,1,2,3},{0,1,3,2},{0,2,1,3},{0,2,3,1},{0,3,1,2},{0,3,2,1},
  {1,0,2,3},{1,0,3,2},{1,2,0,3},{1,2,3,0},{1,3,0,2},{1,3,2,0},
  {2,0,1,3},{2,0,3,1},{2,1,0,3},{2,1,3,0},{2,3,0,1},{2,3,1,0},
  {3,0,1,2},{3,0,2,1},{3,1,0,2},{3,1,2,0},{3,2,0,1},{3,2,1,0}
};

// one wave per (b,f): lanes split r, shuffle-reduce
__global__ __launch_bounds__(64) void hmean_kernel(const float* __restrict__ features,
                                                   float* __restrict__ out) {
  int bf = blockIdx.x;
  int b = bf / FDIM, f = bf - b * FDIM;
  int lane = threadIdx.x;
  const float* fb = features + (size_t)b * NN * FDIM + f;
  float acc = 0.f;
  for (int r = lane; r < NN; r += 64) {
    int w = 0;
#pragma unroll
    for (int a = 0; a < KK; ++a) {
      int i0 = r - a * DD;
      if (0 <= i0 && i0 < NH) w++;
    }
    acc += (float)w * fb[(size_t)r * FDIM];
  }
#pragma unroll
  for (int off = 32; off > 0; off >>= 1) acc += __shfl_down(acc, off, 64);
  if (lane == 0) out[bf] = acc * (2.0f / (float)NH);
}

// grid: (NCH2, B*CIN*OG). Each thread: s0 = blk*512+t, s1 = s0+256 packed as
// float2; COUT/OG o's. Pair-DP perm loop. Per-wave softmax partials (m,l).
__global__ __launch_bounds__(256) void sims_kernel(
    const float* __restrict__ graph, const float* __restrict__ types,
    const float* __restrict__ ksA, const float* __restrict__ krA,
    const float* __restrict__ kcA, float* __restrict__ simsOut,
    float* __restrict__ partial)
{
  __shared__ float ls[COUT * CIN * 16];
  __shared__ float lr[COUT * CIN * 4];
  __shared__ float lc[COUT * CIN * 4];
  __shared__ float lK2[COUT * CIN];
  int t = threadIdx.x;
  for (int i = t; i < COUT * CIN * 16; i += 256) ls[i] = ksA[i];
  for (int i = t; i < COUT * CIN * 4; i += 256) { lr[i] = krA[i]; lc[i] = kcA[i]; }
  __syncthreads();
  if (t < COUT * CIN) {
    float k2 = 0.f;
#pragma unroll
    for (int u = 0; u < 16; ++u) k2 += ls[t * 16 + u] * ls[t * 16 + u];
#pragma unroll
    for (int u = 0; u < 4; ++u) k2 += lr[t * 4 + u] * lr[t * 4 + u] + lc[t * 4 + u] * lc[t * 4 + u];
    lK2[t] = k2;
  }
  __syncthreads();

  int s0r = blockIdx.x * 512 + t;
  int s1r = s0r + 256;
  bool v0 = (s0r < NSUB), v1 = (s1r < NSUB);
  int s0 = v0 ? s0r : (NSUB - 1);
  int s1 = v1 ? s1r : (NSUB - 1);
  int yi  = blockIdx.y;
  int og  = yi >> 3;
  int bci = yi & 7;
  int b   = bci >> 2;
  int ci  = bci & 3;
  int ii0 = s0 / NH, jj0 = s0 - ii0 * NH;
  int ii1 = s1 / NH, jj1 = s1 - ii1 * NH;

  const float* gi = graph + ((size_t)b * CIN + ci) * NN * NN;
  const float* ti = types + ((size_t)b * CIN + ci) * NN;

  v2f subv[16], rtv[4], ctv[4];
  v2f G2 = 0.f, T2r = 0.f, T2c = 0.f;
#pragma unroll
  for (int a = 0; a < KK; ++a) {
    const float* r0 = gi + (size_t)(ii0 + a * DD) * NN + jj0;
    const float* r1 = gi + (size_t)(ii1 + a * DD) * NN + jj1;
#pragma unroll
    for (int bb = 0; bb < KK; ++bb) {
      v2f v; v.x = r0[bb * DD]; v.y = r1[bb * DD];
      subv[a * 4 + bb] = v;
      G2 += v * v;
    }
    v2f rv; rv.x = ti[ii0 + a * DD]; rv.y = ti[ii1 + a * DD];
    v2f cv; cv.x = ti[jj0 + a * DD]; cv.y = ti[jj1 + a * DD];
    rtv[a] = rv; ctv[a] = cv;
    T2r += rv * rv; T2c += cv * cv;
  }
  v2f base0 = G2 + T2r + T2c;

  int wave = t >> 6, lane = t & 63;

#pragma unroll 1
  for (int oo = 0; oo < COUT / OG; ++oo) {
    int o = og * (COUT / OG) + oo;
    int oc = o * CIN + ci;
    float kS[16], kR[4], kC[4];
    {
      const float4* pS4 = (const float4*)(ls + oc * 16);
#pragma unroll
      for (int u = 0; u < 4; ++u) {
        float4 q = pS4[u];
        kS[u*4+0] = q.x; kS[u*4+1] = q.y; kS[u*4+2] = q.z; kS[u*4+3] = q.w;
      }
      float4 qr = *(const float4*)(lr + oc * 4);
      kR[0] = qr.x; kR[1] = qr.y; kR[2] = qr.z; kR[3] = qr.w;
      float4 qc = *(const float4*)(lc + oc * 4);
      kC[0] = qc.x; kC[1] = qc.y; kC[2] = qc.z; kC[3] = qc.w;
    }

    // C1[a][a'] = diag + row + col contribution for mapping a->a'
    v2f C1[16];
#pragma unroll
    for (int a = 0; a < 4; ++a)
#pragma unroll
      for (int ap = 0; ap < 4; ++ap)
        C1[a * 4 + ap] = subv[a * 4 + a] * kS[ap * 4 + ap]
                       + rtv[a] * kR[ap] + ctv[a] * kC[ap];

    // pair-DP: pair01[x][y] covers positions {0,1} -> (x,y); pair23 likewise.
    v2f pair01[16], pair23[16];
#pragma unroll
    for (int x = 0; x < 4; ++x)
#pragma unroll
      for (int y = 0; y < 4; ++y) {
        if (x == y) continue;
        pair01[x * 4 + y] = C1[0 * 4 + x] + C1[1 * 4 + y]
                          + subv[0*4+1] * kS[x*4+y] + subv[1*4+0] * kS[y*4+x];
        pair23[x * 4 + y] = C1[2 * 4 + x] + C1[3 * 4 + y]
                          + subv[2*4+3] * kS[x*4+y] + subv[3*4+2] * kS[y*4+x];
      }

    v2f maxcr = NEGBIG;
#pragma unroll
    for (int p = 0; p < NPERM; ++p) {
      const int p0 = PERM[p][0], p1 = PERM[p][1], p2 = PERM[p][2], p3 = PERM[p][3];
      v2f cr = pair01[p0 * 4 + p1] + pair23[p2 * 4 + p3];
      cr += subv[0*4+2] * kS[p0*4+p2];
      cr += subv[2*4+0] * kS[p2*4+p0];
      cr += subv[0*4+3] * kS[p0*4+p3];
      cr += subv[3*4+0] * kS[p3*4+p0];
      cr += subv[1*4+2] * kS[p1*4+p2];
      cr += subv[2*4+1] * kS[p2*4+p1];
      cr += subv[1*4+3] * kS[p1*4+p3];
      cr += subv[3*4+1] * kS[p3*4+p1];
      maxcr = __builtin_elementwise_max(maxcr, cr);
    }
    v2f best = base0 + lK2[oc] - 2.0f * maxcr;

    int rowIdx = (b * COUT + o) * CIN + ci;
    size_t rowbase = (size_t)rowIdx * NSUB;
    if (v0) simsOut[rowbase + s0r] = best.x;
    if (v1) simsOut[rowbase + s1r] = best.y;

    // per-wave softmax partial (m, l): shuffles only, no syncthreads
    float bm0 = v0 ? best.x : NEGBIG;
    float bm1 = v1 ? best.y : NEGBIG;
    float m = fmaxf(bm0, bm1);
#pragma unroll
    for (int off = 32; off > 0; off >>= 1) m = fmaxf(m, __shfl_down(m, off, 64));
    m = __shfl(m, 0, 64);
    float e = 0.f;
    if (v0) e += __expf(bm0 - m);
    if (v1) e += __expf(bm1 - m);
#pragma unroll
    for (int off = 32; off > 0; off >>= 1) e += __shfl_down(e, off, 64);
    if (lane == 0) {
      int idx = ((rowIdx * NCH2 + blockIdx.x) * NW + wave) * 2;
      partial[idx] = m; partial[idx + 1] = e;
    }
  }
}

// fused: per-block row-stat reduction (372 partials, L2-broadcast) + in-place
// transform of this block's chunk. grid = NROWS*MB.
__global__ __launch_bounds__(256) void softmax_final(float* __restrict__ sims,
                                                     const float* __restrict__ partial) {
  int blk = blockIdx.x;
  int row = blk / MB;
  int ch  = blk - row * MB;
  int t = threadIdx.x;

  const float* pp = partial + (size_t)row * NPART * 2;
  float m = NEGBIG, l = 0.f;
  for (int i = t; i < NPART; i += 256) {
    float mi = pp[2 * i], li = pp[2 * i + 1];
    float M = fmaxf(m, mi);
    l = l * __expf(m - M) + li * __expf(mi - M);
    m = M;
  }
  __shared__ float ms[256], lsv[256];
  ms[t] = m; lsv[t] = l;
  __syncthreads();
  for (int off = 128; off > 0; off >>= 1) {
    if (t < off) {
      float m2 = ms[t + off], l2 = lsv[t + off];
      float M = fmaxf(ms[t], m2);
      lsv[t] = lsv[t] * __expf(ms[t] - M) + l2 * __expf(m2 - M);
      ms[t] = M;
    }
    __syncthreads();
  }
  float M = ms[0], invS = 1.0f / lsv[0];

  int base4 = ch * CH4;
  int n4 = NSUB4 - base4; if (n4 > CH4) n4 = CH4;
  float4* rp = (float4*)(sims + (size_t)row * NSUB) + base4;
  const float scale = 1.0f / (float)NSUB;
  for (int i = t; i < n4; i += 256) {
    float4 v = rp[i];
    v.x = (1.0f - __expf(v.x - M) * invS) * scale;
    v.y = (1.0f - __expf(v.y - M) * invS) * scale;
    v.z = (1.0f - __expf(v.z - M) * invS) * scale;
    v.w = (1.0f - __expf(v.w - M) * invS) * scale;
    rp[i] = v;
  }
}

extern "C" void kernel_launch(void* const* d_in, const int* in_sizes, int n_in,
                              void* d_out, int out_size, void* d_ws, size_t ws_size,
                              hipStream_t stream) {
  const float* graph    = (const float*)d_in[0];
  const float* types    = (const float*)d_in[1];
  const float* features = (const float*)d_in[2];
  const float* ks       = (const float*)d_in[3];
  const float* kr       = (const float*)d_in[4];
  const float* kc       = (const float*)d_in[5];
  float* out  = (float*)d_out;
  float* sims = out + B_ * FDIM;

  float* partial = (float*)d_ws;   // NROWS*NPART*2 floats (~190 KB)

  hmean_kernel<<<B_ * FDIM, 64, 0, stream>>>(features, out);
  dim3 sgrid(NCH2, B_ * CIN * OG);
  sims_kernel<<<sgrid, 256, 0, stream>>>(graph, types, ks, kr, kc, sims, partial);
  softmax_final<<<NROWS * MB, 256, 0, stream>>>(sims, partial);
}

// Round 8
// 100.776 us; speedup vs baseline: 1.2103x; 1.0286x over previous
//
#include <hip/hip_runtime.h>
#include <hip/hip_bf16.h>

#define B_    2
#define CIN   4
#define COUT  8
#define KK    4
#define DD    2
#define NN    224
#define FDIM  128
#define NH    218
#define NSUB  (NH*NH)         // 47524
#define NPERM 24
#define NROWS (B_*COUT*CIN)   // 64 softmax rows
#define NSUB4 (NSUB/4)        // 11881 float4s per row
#define CH4   512             // float4s per chunk
#define MB    ((NSUB4 + CH4 - 1) / CH4)   // 24 chunk-blocks per row
#define OG    2               // o-split; each thread handles COUT/OG = 4 o's
#define NCH2  ((NSUB + 511) / 512)        // 93 s-chunks (512 s per block, 2/thread)
#define NEGBIG (-3.4e38f)

typedef float v2f __attribute__((ext_vector_type(2)));

__device__ static constexpr int PERM[NPERM][4] = {
  {0,1,2,3},{0,1,3,2},{0,2,1,3},{0,2,3,1},{0,3,1,2},{0,3,2,1},
  {1,0,2,3},{1,0,3,2},{1,2,0,3},{1,2,3,0},{1,3,0,2},{1,3,2,0},
  {2,0,1,3},{2,0,3,1},{2,1,0,3},{2,1,3,0},{2,3,0,1},{2,3,1,0},
  {3,0,1,2},{3,0,2,1},{3,1,0,2},{3,1,2,0},{3,2,0,1},{3,2,1,0}
};

// one wave per (b,f): lanes split r, shuffle-reduce
__global__ __launch_bounds__(64) void hmean_kernel(const float* __restrict__ features,
                                                   float* __restrict__ out) {
  int bf = blockIdx.x;
  int b = bf / FDIM, f = bf - b * FDIM;
  int lane = threadIdx.x;
  const float* fb = features + (size_t)b * NN * FDIM + f;
  float acc = 0.f;
  for (int r = lane; r < NN; r += 64) {
    int w = 0;
#pragma unroll
    for (int a = 0; a < KK; ++a) {
      int i0 = r - a * DD;
      if (0 <= i0 && i0 < NH) w++;
    }
    acc += (float)w * fb[(size_t)r * FDIM];
  }
#pragma unroll
  for (int off = 32; off > 0; off >>= 1) acc += __shfl_down(acc, off, 64);
  if (lane == 0) out[bf] = acc * (2.0f / (float)NH);
}

// grid: (NCH2, B*CIN*OG). Pure compute: each thread s0 = blk*512+t, s1 = s0+256
// packed as float2 (v_pk_fma_f32); 4 o's via pair-DP perm loop. No stats.
__global__ __launch_bounds__(256, 4) void sims_kernel(
    const float* __restrict__ graph, const float* __restrict__ types,
    const float* __restrict__ ksA, const float* __restrict__ krA,
    const float* __restrict__ kcA, float* __restrict__ simsOut)
{
  __shared__ float ls[COUT * CIN * 16];
  __shared__ float lr[COUT * CIN * 4];
  __shared__ float lc[COUT * CIN * 4];
  __shared__ float lK2[COUT * CIN];
  int t = threadIdx.x;
  for (int i = t; i < COUT * CIN * 16; i += 256) ls[i] = ksA[i];
  for (int i = t; i < COUT * CIN * 4; i += 256) { lr[i] = krA[i]; lc[i] = kcA[i]; }
  __syncthreads();
  if (t < COUT * CIN) {
    float k2 = 0.f;
#pragma unroll
    for (int u = 0; u < 16; ++u) k2 += ls[t * 16 + u] * ls[t * 16 + u];
#pragma unroll
    for (int u = 0; u < 4; ++u) k2 += lr[t * 4 + u] * lr[t * 4 + u] + lc[t * 4 + u] * lc[t * 4 + u];
    lK2[t] = k2;
  }
  __syncthreads();

  int s0r = blockIdx.x * 512 + t;
  int s1r = s0r + 256;
  bool v0 = (s0r < NSUB), v1 = (s1r < NSUB);
  int s0 = v0 ? s0r : (NSUB - 1);
  int s1 = v1 ? s1r : (NSUB - 1);
  int yi  = blockIdx.y;
  int og  = yi >> 3;
  int bci = yi & 7;
  int b   = bci >> 2;
  int ci  = bci & 3;
  int ii0 = s0 / NH, jj0 = s0 - ii0 * NH;
  int ii1 = s1 / NH, jj1 = s1 - ii1 * NH;

  const float* gi = graph + ((size_t)b * CIN + ci) * NN * NN;
  const float* ti = types + ((size_t)b * CIN + ci) * NN;

  v2f subv[16], rtv[4], ctv[4];
  v2f G2 = 0.f, T2r = 0.f, T2c = 0.f;
#pragma unroll
  for (int a = 0; a < KK; ++a) {
    const float* r0 = gi + (size_t)(ii0 + a * DD) * NN + jj0;
    const float* r1 = gi + (size_t)(ii1 + a * DD) * NN + jj1;
#pragma unroll
    for (int bb = 0; bb < KK; ++bb) {
      v2f v; v.x = r0[bb * DD]; v.y = r1[bb * DD];
      subv[a * 4 + bb] = v;
      G2 += v * v;
    }
    v2f rv; rv.x = ti[ii0 + a * DD]; rv.y = ti[ii1 + a * DD];
    v2f cv; cv.x = ti[jj0 + a * DD]; cv.y = ti[jj1 + a * DD];
    rtv[a] = rv; ctv[a] = cv;
    T2r += rv * rv; T2c += cv * cv;
  }
  v2f base0 = G2 + T2r + T2c;

#pragma unroll 1
  for (int oo = 0; oo < COUT / OG; ++oo) {
    int o = og * (COUT / OG) + oo;
    int oc = o * CIN + ci;
    float kS[16], kR[4], kC[4];
    {
      const float4* pS4 = (const float4*)(ls + oc * 16);
#pragma unroll
      for (int u = 0; u < 4; ++u) {
        float4 q = pS4[u];
        kS[u*4+0] = q.x; kS[u*4+1] = q.y; kS[u*4+2] = q.z; kS[u*4+3] = q.w;
      }
      float4 qr = *(const float4*)(lr + oc * 4);
      kR[0] = qr.x; kR[1] = qr.y; kR[2] = qr.z; kR[3] = qr.w;
      float4 qc = *(const float4*)(lc + oc * 4);
      kC[0] = qc.x; kC[1] = qc.y; kC[2] = qc.z; kC[3] = qc.w;
    }

    // C1[a][a'] = diag + row + col contribution for mapping a->a'
    v2f C1[16];
#pragma unroll
    for (int a = 0; a < 4; ++a)
#pragma unroll
      for (int ap = 0; ap < 4; ++ap)
        C1[a * 4 + ap] = subv[a * 4 + a] * kS[ap * 4 + ap]
                       + rtv[a] * kR[ap] + ctv[a] * kC[ap];

    // pair-DP: pair01[x][y] covers positions {0,1} -> (x,y); pair23 likewise.
    v2f pair01[16], pair23[16];
#pragma unroll
    for (int x = 0; x < 4; ++x)
#pragma unroll
      for (int y = 0; y < 4; ++y) {
        if (x == y) continue;
        pair01[x * 4 + y] = C1[0 * 4 + x] + C1[1 * 4 + y]
                          + subv[0*4+1] * kS[x*4+y] + subv[1*4+0] * kS[y*4+x];
        pair23[x * 4 + y] = C1[2 * 4 + x] + C1[3 * 4 + y]
                          + subv[2*4+3] * kS[x*4+y] + subv[3*4+2] * kS[y*4+x];
      }

    v2f maxcr = NEGBIG;
#pragma unroll
    for (int p = 0; p < NPERM; ++p) {
      const int p0 = PERM[p][0], p1 = PERM[p][1], p2 = PERM[p][2], p3 = PERM[p][3];
      v2f cr = pair01[p0 * 4 + p1] + pair23[p2 * 4 + p3];
      cr += subv[0*4+2] * kS[p0*4+p2];
      cr += subv[2*4+0] * kS[p2*4+p0];
      cr += subv[0*4+3] * kS[p0*4+p3];
      cr += subv[3*4+0] * kS[p3*4+p0];
      cr += subv[1*4+2] * kS[p1*4+p2];
      cr += subv[2*4+1] * kS[p2*4+p1];
      cr += subv[1*4+3] * kS[p1*4+p3];
      cr += subv[3*4+1] * kS[p3*4+p1];
      maxcr = __builtin_elementwise_max(maxcr, cr);
    }
    v2f best = base0 + lK2[oc] - 2.0f * maxcr;

    size_t rowbase = (size_t)((b * COUT + o) * CIN + ci) * NSUB;
    if (v0) simsOut[rowbase + s0r] = best.x;
    if (v1) simsOut[rowbase + s1r] = best.y;
  }
}

// grid (MB, NROWS): per-chunk (m, sumexp) partials, float4 streaming.
__global__ __launch_bounds__(256) void softmax_partial(const float* __restrict__ sims,
                                                       float* __restrict__ partial) {
  int ch = blockIdx.x, row = blockIdx.y;
  int base4 = ch * CH4;
  int n4 = NSUB4 - base4; if (n4 > CH4) n4 = CH4;
  const float4* rp = (const float4*)(sims + (size_t)row * NSUB) + base4;
  int t = threadIdx.x;
  int wave = t >> 6, lane = t & 63;

  float4 a0, a1;
  bool h0 = (t < n4), h1 = (t + 256 < n4);
  if (h0) a0 = rp[t];
  if (h1) a1 = rp[t + 256];

  float m = NEGBIG;
  if (h0) m = fmaxf(fmaxf(a0.x, a0.y), fmaxf(a0.z, a0.w));
  if (h1) m = fmaxf(m, fmaxf(fmaxf(a1.x, a1.y), fmaxf(a1.z, a1.w)));
#pragma unroll
  for (int off = 32; off > 0; off >>= 1) m = fmaxf(m, __shfl_down(m, off, 64));
  __shared__ float red[8];
  if (lane == 0) red[wave] = m;
  __syncthreads();
  float M = fmaxf(fmaxf(red[0], red[1]), fmaxf(red[2], red[3]));

  float e = 0.f;
  if (h0) e  = __expf(a0.x - M) + __expf(a0.y - M) + __expf(a0.z - M) + __expf(a0.w - M);
  if (h1) e += __expf(a1.x - M) + __expf(a1.y - M) + __expf(a1.z - M) + __expf(a1.w - M);
#pragma unroll
  for (int off = 32; off > 0; off >>= 1) e += __shfl_down(e, off, 64);
  if (lane == 0) red[4 + wave] = e;
  __syncthreads();
  if (t == 0) {
    int idx = (row * MB + ch) * 2;
    partial[idx] = M;
    partial[idx + 1] = red[4] + red[5] + red[6] + red[7];
  }
}

// grid (MB, NROWS): fused combine (MB partials per row) + in-place transform.
__global__ __launch_bounds__(256) void softmax_final(float* __restrict__ sims,
                                                     const float* __restrict__ partial) {
  int ch = blockIdx.x, row = blockIdx.y;
  int t = threadIdx.x;

  __shared__ float sM, sInv;
  if (t < 64) {
    const float* pp = partial + row * MB * 2;
    float m = NEGBIG, l = 0.f;
    if (t < MB) { m = pp[2 * t]; l = pp[2 * t + 1]; }
#pragma unroll
    for (int off = 32; off > 0; off >>= 1) {
      float m2 = __shfl_down(m, off, 64);
      float l2 = __shfl_down(l, off, 64);
      float M = fmaxf(m, m2);
      l = l * __expf(m - M) + l2 * __expf(m2 - M);
      m = M;
    }
    if (t == 0) { sM = m; sInv = 1.0f / l; }
  }
  __syncthreads();
  float M = sM, invS = sInv;

  int base4 = ch * CH4;
  int n4 = NSUB4 - base4; if (n4 > CH4) n4 = CH4;
  float4* rp = (float4*)(sims + (size_t)row * NSUB) + base4;
  const float scale = 1.0f / (float)NSUB;
  for (int i = t; i < n4; i += 256) {
    float4 v = rp[i];
    v.x = (1.0f - __expf(v.x - M) * invS) * scale;
    v.y = (1.0f - __expf(v.y - M) * invS) * scale;
    v.z = (1.0f - __expf(v.z - M) * invS) * scale;
    v.w = (1.0f - __expf(v.w - M) * invS) * scale;
    rp[i] = v;
  }
}

extern "C" void kernel_launch(void* const* d_in, const int* in_sizes, int n_in,
                              void* d_out, int out_size, void* d_ws, size_t ws_size,
                              hipStream_t stream) {
  const float* graph    = (const float*)d_in[0];
  const float* types    = (const float*)d_in[1];
  const float* features = (const float*)d_in[2];
  const float* ks       = (const float*)d_in[3];
  const float* kr       = (const float*)d_in[4];
  const float* kc       = (const float*)d_in[5];
  float* out  = (float*)d_out;
  float* sims = out + B_ * FDIM;

  float* partial = (float*)d_ws;   // NROWS*MB*2 floats (~12 KB)

  hmean_kernel<<<B_ * FDIM, 64, 0, stream>>>(features, out);
  dim3 sgrid(NCH2, B_ * CIN * OG);
  sims_kernel<<<sgrid, 256, 0, stream>>>(graph, types, ks, kr, kc, sims);
  dim3 pgrid(MB, NROWS);
  softmax_partial<<<pgrid, 256, 0, stream>>>(sims, partial);
  softmax_final<<<pgrid, 256, 0, stream>>>(sims, partial);
}